// Round 32
// baseline (114806.641 us; speedup 1.0000x reference)
//
#include <hip/hip_runtime.h>

constexpr int kNB = 64;    // batch
constexpr int kNS = 512;   // encoder sequence length
constexpr int kNH = 512;   // hidden dim
constexpr int kNG = 2048;  // 4*kNH gate rows
constexpr int kNT = 512;   // decoder steps

typedef _Float16 chpn_f16;

__device__ __forceinline__ float chpn_sigmoid(float x) {
    return 1.0f / (1.0f + __expf(-x));
}
__device__ __forceinline__ float chpn_tanh(float x) {
    x = fmaxf(fminf(x, 15.0f), -15.0f);
    float e = __expf(2.0f * x);
    return (e - 1.0f) / (e + 1.0f);
}

// ------- init: fused biases + transposed weight layouts ------------------
// wdT[k][r] (k<512: dWih col k; k>=512: dWhh col k-512), weT[k][r], wqT[j][h]
__global__ void ConvexHullPointerNetwork_57303453663418_kernel(
    const float* ebih, const float* ebhh,
    const float* dbih, const float* dbhh,
    const float* ewhh, const float* dwih, const float* dwhh, const float* wq,
    float* enc_b, float* dec_b, float* weT, float* wdT, float* wqT)
{
    size_t i = (size_t)blockIdx.x * 256 + threadIdx.x;
    size_t stride = (size_t)gridDim.x * 256;
    for (size_t x = i; x < (size_t)kNG; x += stride) {
        enc_b[x] = ebih[x] + ebhh[x];
        dec_b[x] = dbih[x] + dbhh[x];
    }
    for (size_t x = i; x < (size_t)kNH * kNG; x += stride) {   // weT
        size_t k = x / kNG, r = x % kNG;
        weT[x] = ewhh[r * kNH + k];
    }
    for (size_t x = i; x < (size_t)2 * kNH * kNG; x += stride) { // wdT
        size_t k = x / kNG, r = x % kNG;
        wdT[x] = (k < kNH) ? dwih[r * kNH + k] : dwhh[r * kNH + (k - kNH)];
    }
    for (size_t x = i; x < (size_t)kNH * kNH; x += stride) {   // wqT
        size_t j = x / kNH, h = x % kNH;
        wqT[x] = wq[h * kNH + j];
    }
}

// ======= encoder: 64 blocks (1 batch each) x 1024 thr, full 512-step loop
__global__ __launch_bounds__(1024) void chpn_enc_loop(
    const float* __restrict__ inputs, const float* __restrict__ wih,
    const float* __restrict__ weT, const float* __restrict__ bias,
    float* __restrict__ hfin, float* __restrict__ cfin,
    chpn_f16* __restrict__ enc_outs)
{
    __shared__ float h_l[kNH];
    __shared__ float c_l[kNH];
    __shared__ float gates[kNG];
    const int tid = threadIdx.x;
    const int b = (int)blockIdx.x;
    const int r0 = tid, r1 = tid + 1024;

    if (tid < kNH) { h_l[tid] = 0.f; c_l[tid] = 0.f; }
    __syncthreads();

    const float b0 = bias[r0], b1 = bias[r1];
    const float w00 = wih[r0 * 2], w01 = wih[r0 * 2 + 1];
    const float w10 = wih[r1 * 2], w11 = wih[r1 * 2 + 1];

    for (int t = 0; t < kNS; ++t) {
        float a0 = 0.f, a1 = 0.f;
        const float* wp = weT;
        #pragma unroll 4
        for (int k = 0; k < kNH; ++k) {
            float hk = h_l[k];
            a0 = fmaf(wp[r0], hk, a0);
            a1 = fmaf(wp[r1], hk, a1);
            wp += kNG;
        }
        float x0 = inputs[(b * kNS + t) * 2 + 0];
        float x1 = inputs[(b * kNS + t) * 2 + 1];
        a0 += b0 + w00 * x0 + w01 * x1;
        a1 += b1 + w10 * x0 + w11 * x1;
        gates[r0] = a0;
        gates[r1] = a1;
        __syncthreads();
        if (tid < kNH) {
            float gi = gates[tid], gf = gates[kNH + tid];
            float gc = gates[2 * kNH + tid], go = gates[3 * kNH + tid];
            float cc = chpn_sigmoid(gf) * c_l[tid] +
                       chpn_sigmoid(gi) * chpn_tanh(gc);
            float hh = chpn_sigmoid(go) * chpn_tanh(cc);
            c_l[tid] = cc;
            h_l[tid] = hh;
            enc_outs[((size_t)b * kNS + t) * kNH + tid] = (chpn_f16)hh;
        }
        __syncthreads();
    }
    if (tid < kNH) {
        hfin[b * kNH + tid] = h_l[tid];
        cfin[b * kNH + tid] = c_l[tid];
    }
}

// -------- keysT[b][h][s] GEMM (fp16 in/out) ------------------------------
__global__ __launch_bounds__(256) void chpn_keys_gemm(
    const chpn_f16* __restrict__ enc_outs, const float* __restrict__ wk,
    chpn_f16* __restrict__ keysT)
{
    int bid = blockIdx.x;
    int bb = bid >> 6, ht = (bid >> 3) & 7, st = bid & 7;
    __shared__ float asb[32][66];
    __shared__ float bsb[32][66];
    int tid = threadIdx.x;
    int tx = tid & 15, ty = tid >> 4;
    float acc[4][4] = {};
    for (int j0 = 0; j0 < kNH; j0 += 32) {
        for (int i = 0; i < 8; ++i) {
            int e = tid + i * 256;
            int j = e & 31, s = e >> 5;
            asb[j][s] = (float)enc_outs[((size_t)bb * kNS + st * 64 + s) * kNH + j0 + j];
            bsb[j][s] = wk[(size_t)(ht * 64 + s) * kNH + j0 + j];
        }
        __syncthreads();
        #pragma unroll 8
        for (int j = 0; j < 32; ++j) {
            float a0 = asb[j][tx*4], a1 = asb[j][tx*4+1], a2 = asb[j][tx*4+2], a3 = asb[j][tx*4+3];
            float b0 = bsb[j][ty*4], b1 = bsb[j][ty*4+1], b2 = bsb[j][ty*4+2], b3 = bsb[j][ty*4+3];
            acc[0][0] = fmaf(b0,a0,acc[0][0]); acc[0][1] = fmaf(b0,a1,acc[0][1]);
            acc[0][2] = fmaf(b0,a2,acc[0][2]); acc[0][3] = fmaf(b0,a3,acc[0][3]);
            acc[1][0] = fmaf(b1,a0,acc[1][0]); acc[1][1] = fmaf(b1,a1,acc[1][1]);
            acc[1][2] = fmaf(b1,a2,acc[1][2]); acc[1][3] = fmaf(b1,a3,acc[1][3]);
            acc[2][0] = fmaf(b2,a0,acc[2][0]); acc[2][1] = fmaf(b2,a1,acc[2][1]);
            acc[2][2] = fmaf(b2,a2,acc[2][2]); acc[2][3] = fmaf(b2,a3,acc[2][3]);
            acc[3][0] = fmaf(b3,a0,acc[3][0]); acc[3][1] = fmaf(b3,a1,acc[3][1]);
            acc[3][2] = fmaf(b3,a2,acc[3][2]); acc[3][3] = fmaf(b3,a3,acc[3][3]);
        }
        __syncthreads();
    }
    for (int i = 0; i < 4; ++i)
        for (int k = 0; k < 4; ++k)
            keysT[((size_t)bb * kNH + ht * 64 + ty * 4 + i) * kNS + st * 64 + tx * 4 + k] =
                (chpn_f16)acc[i][k];
}

// ======= decoder: 64 blocks (1 batch each) x 1024 thr, full 512-step loop
__global__ __launch_bounds__(1024) void chpn_dec_loop(
    const float* __restrict__ wdT, const float* __restrict__ bias,
    const float* __restrict__ wqT, const float* __restrict__ vvec,
    const chpn_f16* __restrict__ keysT, const chpn_f16* __restrict__ enc_outs,
    const float* __restrict__ hfin, const float* __restrict__ cfin,
    float* __restrict__ out)
{
    __shared__ float h_l[kNH];
    __shared__ float c_l[kNH];
    __shared__ float ctx[kNH];
    __shared__ float gates[kNG];
    __shared__ float q_l[kNH];
    __shared__ float qpart[2][kNH];
    __shared__ float vl[kNH];
    __shared__ float el[kNS];
    __shared__ float part[2][kNS];
    __shared__ float cpart[2][kNH];
    __shared__ float dpart[8];
    __shared__ float dinv;

    const int tid = threadIdx.x;
    const int b = (int)blockIdx.x;
    const int r0 = tid, r1 = tid + 1024;
    const float b0 = bias[r0], b1 = bias[r1];
    const int half = tid >> 9;           // 0 or 1
    const int lid = tid & 511;
    const chpn_f16* keyb = keysT + (size_t)b * kNH * kNS;
    const chpn_f16* encb2 = enc_outs + (size_t)b * kNS * kNH;

    if (tid < kNH) {
        h_l[tid] = hfin[b * kNH + tid];
        c_l[tid] = cfin[b * kNH + tid];
        ctx[tid] = 0.f;
        vl[tid] = vvec[tid];
    }
    __syncthreads();

    for (int t = 0; t < kNT; ++t) {
        // ---- CELL: gates = Wih@ctx + Whh@h + b (thread = 2 rows) --------
        float a0 = 0.f, a1 = 0.f;
        {
            const float* wp = wdT;
            #pragma unroll 4
            for (int k = 0; k < kNH; ++k) {           // x half (context)
                float ck = ctx[k];
                a0 = fmaf(wp[r0], ck, a0);
                a1 = fmaf(wp[r1], ck, a1);
                wp += kNG;
            }
            #pragma unroll 4
            for (int k = 0; k < kNH; ++k) {           // h half
                float hk = h_l[k];
                a0 = fmaf(wp[r0], hk, a0);
                a1 = fmaf(wp[r1], hk, a1);
                wp += kNG;
            }
        }
        a0 += b0; a1 += b1;
        gates[r0] = a0;
        gates[r1] = a1;
        __syncthreads();
        if (tid < kNH) {
            float gi = gates[tid], gf = gates[kNH + tid];
            float gc = gates[2 * kNH + tid], go = gates[3 * kNH + tid];
            float cc = chpn_sigmoid(gf) * c_l[tid] +
                       chpn_sigmoid(gi) * chpn_tanh(gc);
            float hh = chpn_sigmoid(go) * chpn_tanh(cc);
            c_l[tid] = cc;
            h_l[tid] = hh;
        }
        __syncthreads();

        // ---- QUERY: q[h] = sum_j wqT[j][h] * h[j]  (split j-halves) -----
        {
            float qa = 0.f;
            const float* wp = wqT + (size_t)half * 256 * kNH + lid;
            #pragma unroll 4
            for (int jx = 0; jx < 256; ++jx)
                qa = fmaf(h_l[half * 256 + jx], wp[(size_t)jx * kNH], qa);
            qpart[half][lid] = qa;
            __syncthreads();
            if (tid < kNH) q_l[tid] = qpart[0][tid] + qpart[1][tid];
            __syncthreads();
        }

        // ---- SCORE: sc[s] = sum_h v[h] tanh(q[h] + keys[h][s]) ----------
        {
            float sa = 0.f;
            const chpn_f16* kp = keyb + (size_t)half * 256 * kNS + lid;
            const int hb = half * 256;
            #pragma unroll 4
            for (int hx = 0; hx < 256; ++hx) {
                float kv = (float)kp[(size_t)hx * kNS];
                sa = fmaf(vl[hb + hx], chpn_tanh(q_l[hb + hx] + kv), sa);
            }
            part[half][lid] = sa;
            __syncthreads();
            if (tid < kNS) {
                float scv = part[0][tid] + part[1][tid];
                out[((size_t)b * kNT + t) * kNS + tid] = scv;
                float e = __expf(scv);             // scores tiny; no max-sub
                el[tid] = e;
                float wsum = e;
                #pragma unroll
                for (int off = 32; off > 0; off >>= 1)
                    wsum += __shfl_down(wsum, off);
                if ((tid & 63) == 0) dpart[tid >> 6] = wsum;
            }
            __syncthreads();
            if (tid == 0) {
                float d = 0.f;
                #pragma unroll
                for (int o = 0; o < 8; ++o) d += dpart[o];
                dinv = 1.0f / d;
            }
            __syncthreads();
        }

        // ---- CTX: ctx[j] = (sum_s el[s] * enc[s][j]) * dinv -------------
        {
            float ca = 0.f;
            const chpn_f16* ep = encb2 + (size_t)half * 256 * kNH + lid;
            #pragma unroll 4
            for (int sx = 0; sx < 256; ++sx)
                ca = fmaf(el[half * 256 + sx], (float)ep[(size_t)sx * kNH], ca);
            cpart[half][lid] = ca;
            __syncthreads();
            if (tid < kNH) ctx[tid] = (cpart[0][tid] + cpart[1][tid]) * dinv;
            __syncthreads();
        }
    }
}

extern "C" void kernel_launch(void* const* d_in, const int* in_sizes, int n_in,
                              void* d_out, int out_size, void* d_ws, size_t ws_size,
                              hipStream_t stream) {
    const float* inputs = (const float*)d_in[0];
    const float* e_wih  = (const float*)d_in[1];
    const float* e_whh  = (const float*)d_in[2];
    const float* e_bih  = (const float*)d_in[3];
    const float* e_bhh  = (const float*)d_in[4];
    const float* d_wih  = (const float*)d_in[5];
    const float* d_whh  = (const float*)d_in[6];
    const float* d_bih  = (const float*)d_in[7];
    const float* d_bhh  = (const float*)d_in[8];
    const float* w_key  = (const float*)d_in[9];
    const float* w_qry  = (const float*)d_in[10];
    const float* v_vec  = (const float*)d_in[11];
    float* out = (float*)d_out;               // f32 output (64 MB)

    float* wsf   = (float*)d_ws;
    float* encb  = wsf;                                   // kNG
    float* decb  = encb + kNG;                            // kNG
    float* wqT   = decb + kNG;                            // kNH*kNH
    float* weT   = wqT + (size_t)kNH * kNH;               // kNH*kNG
    float* wdT   = weT + (size_t)kNH * kNG;               // 2*kNH*kNG
    float* hfin  = wdT + (size_t)2 * kNH * kNG;           // kNB*kNH
    float* cfin  = hfin + (size_t)kNB * kNH;              // kNB*kNH
    chpn_f16* keysH = (chpn_f16*)(cfin + (size_t)kNB * kNH);  // 33.5 MB
    chpn_f16* encH  = keysH + (size_t)kNB * kNH * kNS;        // 33.5 MB

    ConvexHullPointerNetwork_57303453663418_kernel<<<4096, 256, 0, stream>>>(
        e_bih, e_bhh, d_bih, d_bhh, e_whh, d_wih, d_whh, w_qry,
        encb, decb, weT, wdT, wqT);

    chpn_enc_loop<<<64, 1024, 0, stream>>>(inputs, e_wih, weT, encb,
                                           hfin, cfin, encH);

    chpn_keys_gemm<<<4096, 256, 0, stream>>>(encH, w_key, keysH);

    chpn_dec_loop<<<64, 1024, 0, stream>>>(wdT, decb, wqT, v_vec,
                                           keysH, encH, hfin, cfin, out);
}

// Round 34
// 73681.665 us; speedup vs baseline: 1.5581x; 1.5581x over previous
//
#include <hip/hip_runtime.h>

constexpr int kNB = 64;    // batch
constexpr int kNS = 512;   // encoder sequence length
constexpr int kNH = 512;   // hidden dim
constexpr int kNG = 2048;  // 4*kNH gate rows
constexpr int kNT = 512;   // decoder steps

typedef _Float16 chpn_f16;

__device__ __forceinline__ float chpn_sigmoid(float x) {
    return 1.0f / (1.0f + __expf(-x));
}
__device__ __forceinline__ float chpn_tanh(float x) {
    x = fmaxf(fminf(x, 15.0f), -15.0f);
    float e = __expf(2.0f * x);
    return (e - 1.0f) / (e + 1.0f);
}

// ------- init: fused biases + zero h0/c (needs 65536 threads!) -----------
__global__ void ConvexHullPointerNetwork_57303453663418_kernel(
    const float* ebih, const float* ebhh,
    const float* dbih, const float* dbhh,
    float* enc_b, float* dec_b, float* h0c)
{
    int i = blockIdx.x * 256 + threadIdx.x;
    if (i < kNG) { enc_b[i] = ebih[i] + ebhh[i]; dec_b[i] = dbih[i] + dbhh[i]; }
    if (i < 2 * kNB * kNH) h0c[i] = 0.0f;
}

// ------- encoder cell: 512 blocks (1 j each), 256 thr = (b,gate) ---------
__global__ __launch_bounds__(256) void chpn_enc_cell(
    const float* __restrict__ inputs, const float* __restrict__ wih,
    const float* __restrict__ whh, const float* __restrict__ bias,
    const float* __restrict__ h_src, float* __restrict__ h_dst,
    float* __restrict__ c_st, chpn_f16* __restrict__ enc_outs, int t)
{
    __shared__ float tile[64][65];
    __shared__ float gate_lds[4][64];
    const int tid = threadIdx.x;
    const int bb = tid & 63, gg = tid >> 6;
    const int j = (int)blockIdx.x;
    const int r = gg * kNH + j;
    const float* w = whh + (size_t)r * kNH;
    float acc = 0.f;
    for (int ch = 0; ch < 8; ++ch) {
        const int k0 = ch * 64;
        for (int i = 0; i < 16; ++i) {
            int e = tid + i * 256; int kk = e & 63, b2 = e >> 6;
            tile[kk][b2] = h_src[b2 * kNH + k0 + kk];
        }
        __syncthreads();
        #pragma unroll
        for (int kk = 0; kk < 64; ++kk)
            acc = fmaf(tile[kk][bb], w[k0 + kk], acc);
        __syncthreads();
    }
    float x0 = inputs[(bb * kNS + t) * 2 + 0];
    float x1 = inputs[(bb * kNS + t) * 2 + 1];
    acc += bias[r] + wih[r * 2] * x0 + wih[r * 2 + 1] * x1;
    gate_lds[gg][bb] = acc;
    __syncthreads();
    if (tid < 64) {
        float gi = gate_lds[0][tid], gf = gate_lds[1][tid];
        float gc = gate_lds[2][tid], go = gate_lds[3][tid];
        float cc = chpn_sigmoid(gf) * c_st[tid * kNH + j] + chpn_sigmoid(gi) * chpn_tanh(gc);
        float hh = chpn_sigmoid(go) * chpn_tanh(cc);
        c_st[tid * kNH + j] = cc;
        h_dst[tid * kNH + j] = hh;
        enc_outs[((size_t)tid * kNS + t) * kNH + j] = (chpn_f16)hh;
    }
}

// -------- keysT[b][h][s] GEMM (fp16 in/out) ------------------------------
__global__ __launch_bounds__(256) void chpn_keys_gemm(
    const chpn_f16* __restrict__ enc_outs, const float* __restrict__ wk,
    chpn_f16* __restrict__ keysT)
{
    int bid = blockIdx.x;
    int bb = bid >> 6, ht = (bid >> 3) & 7, st = bid & 7;
    __shared__ float asb[32][66];
    __shared__ float bsb[32][66];
    int tid = threadIdx.x;
    int tx = tid & 15, ty = tid >> 4;
    float acc[4][4] = {};
    for (int j0 = 0; j0 < kNH; j0 += 32) {
        for (int i = 0; i < 8; ++i) {
            int e = tid + i * 256;
            int j = e & 31, s = e >> 5;
            asb[j][s] = (float)enc_outs[((size_t)bb * kNS + st * 64 + s) * kNH + j0 + j];
            bsb[j][s] = wk[(size_t)(ht * 64 + s) * kNH + j0 + j];
        }
        __syncthreads();
        #pragma unroll 8
        for (int j = 0; j < 32; ++j) {
            float a0 = asb[j][tx*4], a1 = asb[j][tx*4+1], a2 = asb[j][tx*4+2], a3 = asb[j][tx*4+3];
            float b0 = bsb[j][ty*4], b1 = bsb[j][ty*4+1], b2 = bsb[j][ty*4+2], b3 = bsb[j][ty*4+3];
            acc[0][0] = fmaf(b0,a0,acc[0][0]); acc[0][1] = fmaf(b0,a1,acc[0][1]);
            acc[0][2] = fmaf(b0,a2,acc[0][2]); acc[0][3] = fmaf(b0,a3,acc[0][3]);
            acc[1][0] = fmaf(b1,a0,acc[1][0]); acc[1][1] = fmaf(b1,a1,acc[1][1]);
            acc[1][2] = fmaf(b1,a2,acc[1][2]); acc[1][3] = fmaf(b1,a3,acc[1][3]);
            acc[2][0] = fmaf(b2,a0,acc[2][0]); acc[2][1] = fmaf(b2,a1,acc[2][1]);
            acc[2][2] = fmaf(b2,a2,acc[2][2]); acc[2][3] = fmaf(b2,a3,acc[2][3]);
            acc[3][0] = fmaf(b3,a0,acc[3][0]); acc[3][1] = fmaf(b3,a1,acc[3][1]);
            acc[3][2] = fmaf(b3,a2,acc[3][2]); acc[3][3] = fmaf(b3,a3,acc[3][3]);
        }
        __syncthreads();
    }
    for (int i = 0; i < 4; ++i)
        for (int k = 0; k < 4; ++k)
            keysT[((size_t)bb * kNH + ht * 64 + ty * 4 + i) * kNS + st * 64 + tx * 4 + k] =
                (chpn_f16)acc[i][k];
}

// ------- decoder cell: 512 blocks (1 j each), 256 thr = (b,gate) ---------
__global__ __launch_bounds__(256) void chpn_dec_cell(
    const float* __restrict__ wih, const float* __restrict__ whh,
    const float* __restrict__ bias,
    const float* __restrict__ h_src, float* __restrict__ h_dst,
    float* __restrict__ c_st,
    const float* __restrict__ ctx_num, const float* __restrict__ denom,
    int first)
{
    __shared__ float tile[64][65];
    __shared__ float gate_lds[4][64];
    __shared__ float invd[64];
    const int tid = threadIdx.x;
    const int bb = tid & 63, gg = tid >> 6;
    const int j = (int)blockIdx.x;
    if (tid < 64) invd[tid] = first ? 0.0f : (1.0f / denom[tid]);
    __syncthreads();
    const int r = gg * kNH + j;
    float acc = 0.f;
    {
        const float* w = wih + (size_t)r * kNH;
        for (int ch = 0; ch < 8; ++ch) {
            const int k0 = ch * 64;
            for (int i = 0; i < 16; ++i) {
                int e = tid + i * 256; int kk = e & 63, b2 = e >> 6;
                tile[kk][b2] = first ? 0.0f : ctx_num[b2 * kNH + k0 + kk] * invd[b2];
            }
            __syncthreads();
            #pragma unroll
            for (int kk = 0; kk < 64; ++kk)
                acc = fmaf(tile[kk][bb], w[k0 + kk], acc);
            __syncthreads();
        }
    }
    {
        const float* w = whh + (size_t)r * kNH;
        for (int ch = 0; ch < 8; ++ch) {
            const int k0 = ch * 64;
            for (int i = 0; i < 16; ++i) {
                int e = tid + i * 256; int kk = e & 63, b2 = e >> 6;
                tile[kk][b2] = h_src[b2 * kNH + k0 + kk];
            }
            __syncthreads();
            #pragma unroll
            for (int kk = 0; kk < 64; ++kk)
                acc = fmaf(tile[kk][bb], w[k0 + kk], acc);
            __syncthreads();
        }
    }
    acc += bias[r];
    gate_lds[gg][bb] = acc;
    __syncthreads();
    if (tid < 64) {
        float gi = gate_lds[0][tid], gf = gate_lds[1][tid];
        float gc = gate_lds[2][tid], go = gate_lds[3][tid];
        float cc = chpn_sigmoid(gf) * c_st[tid * kNH + j] + chpn_sigmoid(gi) * chpn_tanh(gc);
        float hh = chpn_sigmoid(go) * chpn_tanh(cc);
        c_st[tid * kNH + j] = cc;
        h_dst[tid * kNH + j] = hh;
    }
}

// ------- query (weight-stationary): 256 blocks = h-pair, 256 thr ---------
// q[b][h] = sum_j wq[h][j] * h[b][j]; also zero ctxn and denom.
__global__ __launch_bounds__(256) void chpn_query_ws(
    const float* __restrict__ wq, const float* __restrict__ h_src,
    float* __restrict__ query, float* __restrict__ ctx_num,
    float* __restrict__ denom)
{
    __shared__ float tile[128][65];     // [j-chunk][b]
    __shared__ float qp[4][2][64];      // [chunk][h01][b]
    const int tid = threadIdx.x;
    const int bb = tid & 63, p = tid >> 6;      // p = chunk handled by thread
    const int h0 = (int)blockIdx.x * 2;
    const float* w0 = wq + (size_t)h0 * kNH;
    const float* w1 = w0 + kNH;

    float a0 = 0.f, a1 = 0.f;
    for (int ch = 0; ch < 4; ++ch) {
        const int j0 = ch * 128;
        for (int i = 0; i < 32; ++i) {
            int e = tid + i * 256; int jj = e & 127, b2 = e >> 7;
            tile[jj][b2] = h_src[b2 * kNH + j0 + jj];
        }
        __syncthreads();
        if (ch == p) {
            #pragma unroll 4
            for (int jj = 0; jj < 128; ++jj) {
                float hv = tile[jj][bb];
                a0 = fmaf(hv, w0[j0 + jj], a0);
                a1 = fmaf(hv, w1[j0 + jj], a1);
            }
        }
        __syncthreads();
    }
    qp[p][0][bb] = a0;
    qp[p][1][bb] = a1;
    __syncthreads();
    if (tid < 128) {
        int b2 = tid & 63, hh = tid >> 6;
        float q = qp[0][hh][b2] + qp[1][hh][b2] + qp[2][hh][b2] + qp[3][hh][b2];
        query[b2 * kNH + h0 + hh] = q;
        ctx_num[b2 * kNH + h0 + hh] = 0.0f;
        if (blockIdx.x == 0 && hh == 0) denom[b2] = 0.0f;
    }
}

// ------- scores + exp + context: 512 blocks x 1024 thr (fp16 reads) ------
__global__ __launch_bounds__(1024) void chpn_score_ctx(
    const chpn_f16* __restrict__ keysT, const chpn_f16* __restrict__ enc_outs,
    const float* __restrict__ query, const float* __restrict__ vvec,
    float* __restrict__ ctx_num, float* __restrict__ denom,
    float* __restrict__ out, int t)
{
    __shared__ float ql[kNH], vl[kNH];
    __shared__ float part[16][64];
    __shared__ float el[64];
    int bid = blockIdx.x;
    int bb = bid >> 3, sc = bid & 7;
    int s0 = sc * 64;
    int tid = threadIdx.x;
    int s = tid & 63, hq = tid >> 6;
    if (tid < kNH) { ql[tid] = query[bb * kNH + tid]; vl[tid] = vvec[tid]; }
    __syncthreads();
    float acc = 0.f;
    const chpn_f16* kp = keysT + (size_t)bb * kNH * kNS + s0 + s;
    const int h0 = hq * 32;
    #pragma unroll 4
    for (int h = h0; h < h0 + 32; ++h) {
        float kv = (float)kp[(size_t)h * kNS];
        acc = fmaf(vl[h], chpn_tanh(ql[h] + kv), acc);
    }
    part[hq][s] = acc;
    __syncthreads();
    if (tid < 64) {
        float scv = 0.f;
        #pragma unroll
        for (int q = 0; q < 16; ++q) scv += part[q][tid];
        out[((size_t)bb * kNT + t) * kNS + s0 + tid] = scv;   // f32 output
        float e = __expf(scv);          // scores tiny; no max-sub needed
        el[tid] = e;
        float wsum = e;
        #pragma unroll
        for (int off = 32; off > 0; off >>= 1) wsum += __shfl_down(wsum, off);
        if (tid == 0) atomicAdd(&denom[bb], wsum);
    }
    __syncthreads();
    int j = tid & 511, sh = tid >> 9;
    float a = 0.f;
    const chpn_f16* ep = enc_outs + ((size_t)bb * kNS + s0 + sh * 32) * kNH + j;
    #pragma unroll 4
    for (int ss = 0; ss < 32; ++ss)
        a = fmaf(el[sh * 32 + ss], (float)ep[(size_t)ss * kNH], a);
    atomicAdd(&ctx_num[bb * kNH + j], a);
}

extern "C" void kernel_launch(void* const* d_in, const int* in_sizes, int n_in,
                              void* d_out, int out_size, void* d_ws, size_t ws_size,
                              hipStream_t stream) {
    const float* inputs = (const float*)d_in[0];
    const float* e_wih  = (const float*)d_in[1];
    const float* e_whh  = (const float*)d_in[2];
    const float* e_bih  = (const float*)d_in[3];
    const float* e_bhh  = (const float*)d_in[4];
    const float* d_wih  = (const float*)d_in[5];
    const float* d_whh  = (const float*)d_in[6];
    const float* d_bih  = (const float*)d_in[7];
    const float* d_bhh  = (const float*)d_in[8];
    const float* w_key  = (const float*)d_in[9];
    const float* w_qry  = (const float*)d_in[10];
    const float* v_vec  = (const float*)d_in[11];
    float* out = (float*)d_out;               // f32 output (64 MB)

    float* wsf   = (float*)d_ws;
    float* h0    = wsf;
    float* cst   = h0 + kNB * kNH;
    float* h1    = cst + kNB * kNH;
    float* query = h1 + kNB * kNH;
    float* ctxn  = query + kNB * kNH;
    float* denom = ctxn + kNB * kNH;
    float* encb  = denom + 64;
    float* decb  = encb + kNG;
    chpn_f16* keysH = (chpn_f16*)(decb + kNG);            // 33.5 MB
    chpn_f16* encH  = keysH + (size_t)kNB * kNH * kNS;    // 33.5 MB

    // 256 blocks x 256 thr = 65536 threads: covers 2*kNB*kNH zeroing exactly
    ConvexHullPointerNetwork_57303453663418_kernel<<<256, 256, 0, stream>>>(
        e_bih, e_bhh, d_bih, d_bhh, encb, decb, h0);

    for (int t = 0; t < kNS; ++t) {
        float* hs = (t & 1) ? h1 : h0;
        float* hd = (t & 1) ? h0 : h1;
        chpn_enc_cell<<<512, 256, 0, stream>>>(inputs, e_wih, e_whh, encb,
                                               hs, hd, cst, encH, t);
    }

    chpn_keys_gemm<<<4096, 256, 0, stream>>>(encH, w_key, keysH);

    for (int t = 0; t < kNT; ++t) {
        float* hs = (t & 1) ? h1 : h0;
        float* hd = (t & 1) ? h0 : h1;
        chpn_dec_cell<<<512, 256, 0, stream>>>(d_wih, d_whh, decb,
                                               hs, hd, cst,
                                               ctxn, denom, t == 0 ? 1 : 0);
        chpn_query_ws<<<256, 256, 0, stream>>>(w_qry, hd, query, ctxn, denom);
        chpn_score_ctx<<<512, 1024, 0, stream>>>(keysH, encH, query, v_vec,
                                                 ctxn, denom, out, t);
    }
}